// Round 1
// baseline (179.918 us; speedup 1.0000x reference)
//
#include <hip/hip_runtime.h>

#define TX 64        // output tile width
#define TY 16        // output tile height
#define HXV 74       // valid halo width  (TX + 10)
#define HXP 76       // padded halo width (16B-aligned rows for float4 LDS reads)
#define HY 26        // halo height (TY + 10)
#define NT 256
#define IMG 512

// ---------------------------------------------------------------------------
// Fused SSIM tile kernel: per block, compute the 5 Gaussian-filtered moment
// maps (separable 11x11) for a 64x16 tile, the SSIM map, and a partial sum.
// ---------------------------------------------------------------------------
__global__ __launch_bounds__(NT) void ssim_tile_kernel(
    const float* __restrict__ pred,
    const float* __restrict__ target,
    const float* __restrict__ kern,
    float* __restrict__ partial)
{
    __shared__ __align__(16) float sP[HY][HXP];
    __shared__ __align__(16) float sT[HY][HXP];
    __shared__ __align__(16) float sH[5][HY][TX];   // h-filtered: P,T,PP,TT,PT
    __shared__ float sRed[4];

    const int tid = threadIdx.x;
    const int tx0 = blockIdx.x * TX;
    const int ty0 = blockIdx.y * TY;
    const int img = blockIdx.z;

    // 1D gaussian weights from center row of the 2D kernel: k2d[5][j] = g5*gj
    float w[11];
    {
        const float inv_g5 = 1.0f / sqrtf(kern[60]);
        #pragma unroll
        for (int j = 0; j < 11; ++j) w[j] = kern[55 + j] * inv_g5;
    }

    const float* pimg = pred   + (size_t)img * (IMG * IMG);
    const float* timg = target + (size_t)img * (IMG * IMG);

    // ---- phase 0: load halo tile (zero padding outside image) ----
    for (int idx = tid; idx < HY * HXP; idx += NT) {
        int r = idx / HXP;
        int c = idx - r * HXP;
        int gy = ty0 + r - 5;
        int gx = tx0 + c - 5;
        float pv = 0.0f, tv = 0.0f;
        if (c < HXV && (unsigned)gy < IMG && (unsigned)gx < IMG) {
            int o = gy * IMG + gx;
            pv = pimg[o];
            tv = timg[o];
        }
        sP[r][c] = pv;
        sT[r][c] = tv;
    }
    __syncthreads();

    // ---- phase 1: horizontal pass, 4 outputs/thread-group via float4 ----
    for (int g = tid; g < 16 * HY; g += NT) {
        int xg = g & 15;
        int r  = g >> 4;
        int x0 = xg << 2;

        float p[16], t[16];
        *(float4*)&p[0]  = *(const float4*)&sP[r][x0];
        *(float4*)&p[4]  = *(const float4*)&sP[r][x0 + 4];
        *(float4*)&p[8]  = *(const float4*)&sP[r][x0 + 8];
        *(float4*)&p[12] = *(const float4*)&sP[r][x0 + 12];
        *(float4*)&t[0]  = *(const float4*)&sT[r][x0];
        *(float4*)&t[4]  = *(const float4*)&sT[r][x0 + 4];
        *(float4*)&t[8]  = *(const float4*)&sT[r][x0 + 8];
        *(float4*)&t[12] = *(const float4*)&sT[r][x0 + 12];

        float hA[4] = {0,0,0,0}, hB[4] = {0,0,0,0}, hC[4] = {0,0,0,0};
        float hD[4] = {0,0,0,0}, hE[4] = {0,0,0,0};
        #pragma unroll
        for (int k = 0; k < 11; ++k) {
            float wk = w[k];
            #pragma unroll
            for (int d = 0; d < 4; ++d) {
                float pv = p[k + d], tv = t[k + d];
                hA[d] = fmaf(wk, pv,      hA[d]);
                hB[d] = fmaf(wk, tv,      hB[d]);
                hC[d] = fmaf(wk, pv * pv, hC[d]);   // CSE'd across k+d
                hD[d] = fmaf(wk, tv * tv, hD[d]);
                hE[d] = fmaf(wk, pv * tv, hE[d]);
            }
        }
        *(float4*)&sH[0][r][x0] = make_float4(hA[0], hA[1], hA[2], hA[3]);
        *(float4*)&sH[1][r][x0] = make_float4(hB[0], hB[1], hB[2], hB[3]);
        *(float4*)&sH[2][r][x0] = make_float4(hC[0], hC[1], hC[2], hC[3]);
        *(float4*)&sH[3][r][x0] = make_float4(hD[0], hD[1], hD[2], hD[3]);
        *(float4*)&sH[4][r][x0] = make_float4(hE[0], hE[1], hE[2], hE[3]);
    }
    __syncthreads();

    // ---- phase 2: vertical pass (8-row accumulator groups) + SSIM ----
    float lsum = 0.0f;
    if (tid < 128) {
        const int x  = tid & 63;
        const int y0 = (tid >> 6) << 3;   // 0 or 8

        float acc[5][8];
        #pragma unroll
        for (int c = 0; c < 5; ++c)
            #pragma unroll
            for (int j = 0; j < 8; ++j) acc[c][j] = 0.0f;

        #pragma unroll
        for (int rr = 0; rr < 18; ++rr) {
            float v0 = sH[0][y0 + rr][x];
            float v1 = sH[1][y0 + rr][x];
            float v2 = sH[2][y0 + rr][x];
            float v3 = sH[3][y0 + rr][x];
            float v4 = sH[4][y0 + rr][x];
            #pragma unroll
            for (int j = 0; j < 8; ++j) {
                int k = rr - j;                   // compile-time after unroll
                if (k >= 0 && k <= 10) {
                    float wk = w[k];
                    acc[0][j] = fmaf(wk, v0, acc[0][j]);
                    acc[1][j] = fmaf(wk, v1, acc[1][j]);
                    acc[2][j] = fmaf(wk, v2, acc[2][j]);
                    acc[3][j] = fmaf(wk, v3, acc[3][j]);
                    acc[4][j] = fmaf(wk, v4, acc[4][j]);
                }
            }
        }

        #pragma unroll
        for (int j = 0; j < 8; ++j) {
            float mx  = acc[0][j], my = acc[1][j];
            float mxx = mx * mx, myy = my * my, mxy = mx * my;
            float sx  = acc[2][j] - mxx;
            float sy  = acc[3][j] - myy;
            float sxy = acc[4][j] - mxy;
            float num = (2.0f * mxy + 1e-4f) * (2.0f * sxy + 9e-4f);
            float den = (mxx + myy + 1e-4f) * (sx + sy + 9e-4f);
            lsum += num / den;
        }
    }

    // ---- block reduction -> one partial per block ----
    #pragma unroll
    for (int off = 32; off > 0; off >>= 1)
        lsum += __shfl_down(lsum, off, 64);
    if ((tid & 63) == 0) sRed[tid >> 6] = lsum;
    __syncthreads();
    if (tid == 0) {
        int bl = (blockIdx.z * gridDim.y + blockIdx.y) * gridDim.x + blockIdx.x;
        partial[bl] = sRed[0] + sRed[1] + sRed[2] + sRed[3];
    }
}

// ---------------------------------------------------------------------------
// Final reduction: sum partials, out = 1 - mean
// ---------------------------------------------------------------------------
__global__ __launch_bounds__(NT) void ssim_reduce_kernel(
    const float* __restrict__ partial, float* __restrict__ out,
    int n, float inv_npix)
{
    __shared__ float sRed[4];
    float s0 = 0.0f, s1 = 0.0f, s2 = 0.0f, s3 = 0.0f;
    int i = threadIdx.x;
    for (; i + 3 * NT < n; i += 4 * NT) {
        s0 += partial[i];
        s1 += partial[i + NT];
        s2 += partial[i + 2 * NT];
        s3 += partial[i + 3 * NT];
    }
    for (; i < n; i += NT) s0 += partial[i];
    float s = (s0 + s1) + (s2 + s3);
    #pragma unroll
    for (int off = 32; off > 0; off >>= 1)
        s += __shfl_down(s, off, 64);
    if ((threadIdx.x & 63) == 0) sRed[threadIdx.x >> 6] = s;
    __syncthreads();
    if (threadIdx.x == 0)
        out[0] = 1.0f - (sRed[0] + sRed[1] + sRed[2] + sRed[3]) * inv_npix;
}

extern "C" void kernel_launch(void* const* d_in, const int* in_sizes, int n_in,
                              void* d_out, int out_size, void* d_ws, size_t ws_size,
                              hipStream_t stream) {
    const float* pred   = (const float*)d_in[0];
    const float* target = (const float*)d_in[1];
    const float* kern   = (const float*)d_in[2];
    float* out     = (float*)d_out;
    float* partial = (float*)d_ws;   // needs gx*gy*nimg floats (64 KB here)

    const int nimg = in_sizes[0] / (IMG * IMG);   // 64
    dim3 grid(IMG / TX, IMG / TY, nimg);          // 8 x 32 x 64 = 16384 blocks
    const int nblocks = grid.x * grid.y * grid.z;
    const float inv_npix = 1.0f / ((float)nimg * (float)(IMG * IMG));

    ssim_tile_kernel<<<grid, NT, 0, stream>>>(pred, target, kern, partial);
    ssim_reduce_kernel<<<1, NT, 0, stream>>>(partial, out, nblocks, inv_npix);
}

// Round 2
// 112.260 us; speedup vs baseline: 1.6027x; 1.6027x over previous
//
#include <hip/hip_runtime.h>

#define TX 64        // output tile width
#define TY 16        // output tile height
#define HY 26        // halo height (TY + 10)
#define SHP 68       // sH row stride in floats (64 + 4 pad -> conflict-free writes)
#define NT 256
#define IMG 512

// ---------------------------------------------------------------------------
// Fused SSIM tile kernel.
// Phase 1: 208 threads (26 rows x 8 col-groups) read 24 raw pixels/image from
//          global (aligned float4, zero OOB), horizontal-convolve 8 outputs x
//          5 moment channels, write to LDS sH (stride 68 => bank-uniform).
// Phase 2: 128 threads (64 cols x 2 row-groups of 8) vertical-convolve from
//          sH (lane-consecutive b32 reads, conflict-free), SSIM, reduce.
// ---------------------------------------------------------------------------
__global__ __launch_bounds__(NT, 4) void ssim_tile_kernel(
    const float* __restrict__ pred,
    const float* __restrict__ target,
    const float* __restrict__ kern,
    float* __restrict__ partial)
{
    __shared__ __align__(16) float sH[5][HY][SHP];   // h-filtered: P,T,PP,TT,PT
    __shared__ float sRed[4];

    const int tid = threadIdx.x;
    const int tx0 = blockIdx.x * TX;
    const int ty0 = blockIdx.y * TY;
    const int img = blockIdx.z;

    // 1D gaussian weights from center row of the 2D kernel: k2d[5][j] = g5*gj
    float w[11];
    {
        const float inv_g5 = 1.0f / sqrtf(kern[60]);
        #pragma unroll
        for (int j = 0; j < 11; ++j) w[j] = kern[55 + j] * inv_g5;
    }

    // ---- phase 1: global -> registers -> horizontal conv -> sH ----
    if (tid < 208) {
        const int r  = tid >> 3;        // 0..25  (halo row)
        const int xg = tid & 7;         // 0..7   (8-output column group)
        const int gy = ty0 + r - 5;
        const int cb = tx0 + (xg << 3) - 8;   // aligned float4 base (multiple of 4)
        const bool rowok = (unsigned)gy < IMG;

        const float* prow = pred   + (size_t)img * (IMG * IMG) + gy * IMG;
        const float* trow = target + (size_t)img * (IMG * IMG) + gy * IMG;

        float p[24], t[24];
        #pragma unroll
        for (int q = 0; q < 6; ++q) {
            const int c0 = cb + (q << 2);
            float4 pv = make_float4(0.f, 0.f, 0.f, 0.f);
            float4 tv = make_float4(0.f, 0.f, 0.f, 0.f);
            if (rowok && (unsigned)c0 < IMG) {   // c0 % 4 == 0, IMG % 4 == 0
                pv = *(const float4*)(prow + c0);
                tv = *(const float4*)(trow + c0);
            }
            p[q*4+0] = pv.x; p[q*4+1] = pv.y; p[q*4+2] = pv.z; p[q*4+3] = pv.w;
            t[q*4+0] = tv.x; t[q*4+1] = tv.y; t[q*4+2] = tv.z; t[q*4+3] = tv.w;
        }

        // outputs o=0..7 at tile-col xg*8+o; input m=0..17 is p[m+3]
        float hP[8], hT[8], hPP[8], hTT[8], hPT[8];
        #pragma unroll
        for (int o = 0; o < 8; ++o) { hP[o]=0.f; hT[o]=0.f; hPP[o]=0.f; hTT[o]=0.f; hPT[o]=0.f; }
        #pragma unroll
        for (int m = 0; m < 18; ++m) {
            const float pv = p[m + 3], tv = t[m + 3];
            const float pp = pv * pv, tt = tv * tv, pt = pv * tv;
            #pragma unroll
            for (int o = 0; o < 8; ++o) {
                const int k = m - o;            // weight index, compile-time
                if (k >= 0 && k <= 10) {
                    const float wk = w[k];
                    hP [o] = fmaf(wk, pv, hP [o]);
                    hT [o] = fmaf(wk, tv, hT [o]);
                    hPP[o] = fmaf(wk, pp, hPP[o]);
                    hTT[o] = fmaf(wk, tt, hTT[o]);
                    hPT[o] = fmaf(wk, pt, hPT[o]);
                }
            }
        }

        const int x0 = xg << 3;
        *(float4*)&sH[0][r][x0]     = make_float4(hP [0], hP [1], hP [2], hP [3]);
        *(float4*)&sH[0][r][x0 + 4] = make_float4(hP [4], hP [5], hP [6], hP [7]);
        *(float4*)&sH[1][r][x0]     = make_float4(hT [0], hT [1], hT [2], hT [3]);
        *(float4*)&sH[1][r][x0 + 4] = make_float4(hT [4], hT [5], hT [6], hT [7]);
        *(float4*)&sH[2][r][x0]     = make_float4(hPP[0], hPP[1], hPP[2], hPP[3]);
        *(float4*)&sH[2][r][x0 + 4] = make_float4(hPP[4], hPP[5], hPP[6], hPP[7]);
        *(float4*)&sH[3][r][x0]     = make_float4(hTT[0], hTT[1], hTT[2], hTT[3]);
        *(float4*)&sH[3][r][x0 + 4] = make_float4(hTT[4], hTT[5], hTT[6], hTT[7]);
        *(float4*)&sH[4][r][x0]     = make_float4(hPT[0], hPT[1], hPT[2], hPT[3]);
        *(float4*)&sH[4][r][x0 + 4] = make_float4(hPT[4], hPT[5], hPT[6], hPT[7]);
    }
    __syncthreads();

    // ---- phase 2: vertical pass (8-row accumulator groups) + SSIM ----
    float lsum = 0.0f;
    if (tid < 128) {
        const int x  = tid & 63;
        const int y0 = (tid >> 6) << 3;   // 0 or 8

        float acc[5][8];
        #pragma unroll
        for (int c = 0; c < 5; ++c)
            #pragma unroll
            for (int j = 0; j < 8; ++j) acc[c][j] = 0.0f;

        #pragma unroll
        for (int rr = 0; rr < 18; ++rr) {
            const float v0 = sH[0][y0 + rr][x];
            const float v1 = sH[1][y0 + rr][x];
            const float v2 = sH[2][y0 + rr][x];
            const float v3 = sH[3][y0 + rr][x];
            const float v4 = sH[4][y0 + rr][x];
            #pragma unroll
            for (int j = 0; j < 8; ++j) {
                const int k = rr - j;              // compile-time after unroll
                if (k >= 0 && k <= 10) {
                    const float wk = w[k];
                    acc[0][j] = fmaf(wk, v0, acc[0][j]);
                    acc[1][j] = fmaf(wk, v1, acc[1][j]);
                    acc[2][j] = fmaf(wk, v2, acc[2][j]);
                    acc[3][j] = fmaf(wk, v3, acc[3][j]);
                    acc[4][j] = fmaf(wk, v4, acc[4][j]);
                }
            }
        }

        #pragma unroll
        for (int j = 0; j < 8; ++j) {
            const float mx  = acc[0][j], my = acc[1][j];
            const float mxx = mx * mx, myy = my * my, mxy = mx * my;
            const float sx  = acc[2][j] - mxx;
            const float sy  = acc[3][j] - myy;
            const float sxy = acc[4][j] - mxy;
            const float num = (2.0f * mxy + 1e-4f) * (2.0f * sxy + 9e-4f);
            const float den = (mxx + myy + 1e-4f) * (sx + sy + 9e-4f);
            lsum = fmaf(num, __builtin_amdgcn_rcpf(den), lsum);
        }
    }

    // ---- block reduction -> one partial per block ----
    #pragma unroll
    for (int off = 32; off > 0; off >>= 1)
        lsum += __shfl_down(lsum, off, 64);
    if ((tid & 63) == 0) sRed[tid >> 6] = lsum;
    __syncthreads();
    if (tid == 0) {
        const int bl = (blockIdx.z * gridDim.y + blockIdx.y) * gridDim.x + blockIdx.x;
        partial[bl] = sRed[0] + sRed[1] + sRed[2] + sRed[3];
    }
}

// ---------------------------------------------------------------------------
// Final reduction: sum partials, out = 1 - mean
// ---------------------------------------------------------------------------
__global__ __launch_bounds__(NT) void ssim_reduce_kernel(
    const float* __restrict__ partial, float* __restrict__ out,
    int n, float inv_npix)
{
    __shared__ float sRed[4];
    float s = 0.0f;
    const int n4 = n >> 2;
    for (int i = threadIdx.x; i < n4; i += NT) {
        const float4 v = ((const float4*)partial)[i];
        s += (v.x + v.y) + (v.z + v.w);
    }
    for (int i = (n4 << 2) + threadIdx.x; i < n; i += NT) s += partial[i];
    #pragma unroll
    for (int off = 32; off > 0; off >>= 1)
        s += __shfl_down(s, off, 64);
    if ((threadIdx.x & 63) == 0) sRed[threadIdx.x >> 6] = s;
    __syncthreads();
    if (threadIdx.x == 0)
        out[0] = 1.0f - (sRed[0] + sRed[1] + sRed[2] + sRed[3]) * inv_npix;
}

extern "C" void kernel_launch(void* const* d_in, const int* in_sizes, int n_in,
                              void* d_out, int out_size, void* d_ws, size_t ws_size,
                              hipStream_t stream) {
    const float* pred   = (const float*)d_in[0];
    const float* target = (const float*)d_in[1];
    const float* kern   = (const float*)d_in[2];
    float* out     = (float*)d_out;
    float* partial = (float*)d_ws;   // gx*gy*nimg floats (64 KB here)

    const int nimg = in_sizes[0] / (IMG * IMG);   // 64
    dim3 grid(IMG / TX, IMG / TY, nimg);          // 8 x 32 x 64 = 16384 blocks
    const int nblocks = grid.x * grid.y * grid.z;
    const float inv_npix = 1.0f / ((float)nimg * (float)(IMG * IMG));

    ssim_tile_kernel<<<grid, NT, 0, stream>>>(pred, target, kern, partial);
    ssim_reduce_kernel<<<1, NT, 0, stream>>>(partial, out, nblocks, inv_npix);
}